// Round 8
// baseline (231.495 us; speedup 1.0000x reference)
//
#include <hip/hip_runtime.h>
#include <cstdint>
#include <cstddef>

#define BATCH 2048
#define NZ 128
#define NGEN 8
#define GRPS 32                 // samples per group (same generator)
#define MAXG 72                 // max padded groups: ceil((2048+8*31)/32)
#define NCT 13                  // fc2 col tiles of 128 (12 full + 1x32 tail)
#define KS 2                    // fc2 k-split
#define H2_ELEMS 1792           // 32*7*8 (x padded 7->8) per sample, bf16
#define H2_HALF (BATCH * H2_ELEMS)   // elements per k-half partial array
#define WS_H1_OFF 16384                      // h1 region: 72*8192 fp32 = 2.36 MB
#define WS_H2_OFF (16384 + MAXG * 8192 * 4)  // h2 region: 2 halves x 7.17 MB

typedef unsigned int u32;
typedef unsigned short u16;

__device__ __forceinline__ float lrelu(float x) { return fmaxf(x, 0.2f * x); }
__device__ __forceinline__ float bflo(u32 u) { union { u32 i; float f; } v; v.i = u << 16; return v.f; }
__device__ __forceinline__ float bfhi(u32 u) { union { u32 i; float f; } v; v.i = u & 0xffff0000u; return v.f; }
__device__ __forceinline__ float bf1(u16 u) { union { u32 i; float f; } v; v.i = ((u32)u) << 16; return v.f; }
__device__ __forceinline__ u16 f2bf(float f) {
    union { float f; u32 i; } v; v.f = f;
    u32 r = v.i + 0x7fffu + ((v.i >> 16) & 1u);   // round-to-nearest-even
    return (u16)(r >> 16);
}
__device__ __forceinline__ float fast_tanh(float x) {
    x = fminf(fmaxf(x, -9.f), 9.f);
    const float e = __expf(2.f * x);
    return (e - 1.f) / (e + 1.f);
}

// ---------------------------------------------------------------------------
// Kernel 1: bin samples by generator. wsi[0] = padded total;
// wsi[16..16+tot) = sample ids grouped by generator, groups padded to
// multiples of GRPS with -1.
// ---------------------------------------------------------------------------
__global__ void bin_kernel(const int* __restrict__ g_idx, int* __restrict__ wsi) {
    __shared__ int cnt[NGEN];
    __shared__ int pbase[NGEN + 1];
    __shared__ u16 rank[BATCH];
    const int tid = threadIdx.x;
    if (tid < NGEN) cnt[tid] = 0;
    __syncthreads();
    for (int b = tid; b < BATCH; b += 256) {
        int g = g_idx[b];
        rank[b] = (u16)atomicAdd(&cnt[g], 1);
    }
    __syncthreads();
    if (tid == 0) {
        int acc = 0;
        for (int g = 0; g < NGEN; ++g) {
            pbase[g] = acc;
            acc += ((cnt[g] + GRPS - 1) / GRPS) * GRPS;
        }
        pbase[NGEN] = acc;
        wsi[0] = acc;
    }
    __syncthreads();
    const int total = pbase[NGEN];
    for (int i = tid; i < total; i += 256) wsi[16 + i] = -1;
    __syncthreads();
    for (int b = tid; b < BATCH; b += 256) {
        int g = g_idx[b];
        wsi[16 + pbase[g] + (int)rank[b]] = b;
    }
}

// ---------------------------------------------------------------------------
// Kernel 2: FC1 once per group. Block = one group of 32 samples.
// Thread = one h1 column (256 cols). h1g layout [grp][col 256][sample 32] fp32.
// Only 72 blocks — tiny (~5 us); removes all FC1 recompute from fc2.
// ---------------------------------------------------------------------------
__global__ __launch_bounds__(256) void fc1_kernel(
    const float* __restrict__ z, const int* __restrict__ g_idx,
    const float* __restrict__ W1, const float* __restrict__ b1,
    const int* __restrict__ wsi, float* __restrict__ h1g)
{
    __shared__ float zst[NZ][36];   // 18.4 KB, [k][s], b128-aligned stride
    __shared__ int sb[GRPS];
    __shared__ int sG;

    const int tid = threadIdx.x;
    const int grp = blockIdx.x;
    const int base = grp * GRPS;
    if (base >= wsi[0]) return;

    if (tid == 0) sG = g_idx[wsi[16 + base]];
    if (tid < GRPS) sb[tid] = wsi[16 + base + tid];
    __syncthreads();
    const float* W1g = W1 + sG * (NZ * 256);
    const float* b1g = b1 + sG * 256;

    // stage z transposed: lanes read consecutive float4 of one sample
    for (int i4 = tid; i4 < GRPS * 32; i4 += 256) {
        const int s = i4 >> 5, f = i4 & 31;
        float4 v = make_float4(0.f, 0.f, 0.f, 0.f);
        if (sb[s] >= 0) v = *(const float4*)(z + (size_t)sb[s] * NZ + 4 * f);
        zst[4 * f + 0][s] = v.x; zst[4 * f + 1][s] = v.y;
        zst[4 * f + 2][s] = v.z; zst[4 * f + 3][s] = v.w;
    }
    __syncthreads();

    // thread = col c; acc over 32 samples
    const int c = tid;
    float acc[32];
    #pragma unroll
    for (int s = 0; s < 32; ++s) acc[s] = 0.f;
    const float* wp = W1g + c;
    for (int k = 0; k < NZ; ++k) {
        const float w = wp[k * 256];       // lanes -> consecutive cols, coalesced
        #pragma unroll
        for (int q = 0; q < 8; ++q) {
            float4 av = *(const float4*)&zst[k][4 * q];   // broadcast
            acc[4 * q + 0] += av.x * w;
            acc[4 * q + 1] += av.y * w;
            acc[4 * q + 2] += av.z * w;
            acc[4 * q + 3] += av.w * w;
        }
    }
    const float bv = b1g[c];
    float* hp = h1g + (size_t)grp * 8192 + c * 32;
    #pragma unroll
    for (int q = 0; q < 8; ++q) {
        float4 hv;
        hv.x = lrelu(acc[4 * q + 0] + bv);
        hv.y = lrelu(acc[4 * q + 1] + bv);
        hv.z = lrelu(acc[4 * q + 2] + bv);
        hv.w = lrelu(acc[4 * q + 3] + bv);
        *(float4*)(hp + 4 * q) = hv;
    }
}

// ---------------------------------------------------------------------------
// Kernel 3: FC2 tile GEMM. Block = (group, 128-col tile, k-half).
// Thread owns 4 CONSECUTIVE cols x 4 samples: per k-iter exactly
// 1 global_load_dwordx4 (W2, 16B-aligned, 128 B/wave) + 1 ds_read_b128
// (h1, 8-address conflict-free) + 16 FMAs. Writes bf16 PARTIAL (no lrelu;
// summed in conv staging). Bias folded into k-half 0.
// ---------------------------------------------------------------------------
__global__ __launch_bounds__(256, 6) void fc2_kernel(
    const int* __restrict__ g_idx,
    const float* __restrict__ W2, const float* __restrict__ b2,
    const int* __restrict__ wsi, const float* __restrict__ h1g,
    u16* __restrict__ h2g)
{
    __shared__ float h1s[128][36];   // 18.4 KB, [local k][sample]
    __shared__ int sb[GRPS];
    __shared__ int sG;

    const int tid = threadIdx.x;
    const int bx = blockIdx.x;
    const int grp = bx / (NCT * KS);
    const int rem = bx % (NCT * KS);
    const int tile = rem >> 1;
    const int kh = rem & 1;
    const int base = grp * GRPS;
    if (base >= wsi[0]) return;

    if (tid == 0) sG = g_idx[wsi[16 + base]];
    if (tid < GRPS) sb[tid] = wsi[16 + base + tid];
    __syncthreads();
    const float* W2g = W2 + sG * (256 * 1568);
    const float* b2g = b2 + sG * 1568;

    // stage h1 slice [kh*128 .. +128) x 32 samples: coalesced float4 reads
    {
        const float4* h1p = (const float4*)(h1g + (size_t)grp * 8192 + kh * 4096);
        #pragma unroll
        for (int rr = 0; rr < 4; ++rr) {
            const int i4 = tid + 256 * rr;
            const float4 v = h1p[i4];
            const int lk = i4 >> 3;            // 4*i4/32
            const int s0 = (i4 & 7) * 4;
            *(float4*)&h1s[lk][s0] = v;
        }
    }
    __syncthreads();

    const int cq = tid & 7;           // 4-col chunk within 32-col unit
    const int sq = (tid >> 3) & 7;    // sample quad: samples 4sq..4sq+3
    const int t2 = tid >> 6;          // 32-col unit within 128-col tile
    const int col0 = tile * 128 + t2 * 32 + cq * 4;

    if (col0 < 1568) {
        float acc[4][4];              // [col][sample]
        #pragma unroll
        for (int jc = 0; jc < 4; ++jc)
            #pragma unroll
            for (int ds = 0; ds < 4; ++ds) acc[jc][ds] = 0.f;
        const float* wp0 = W2g + (size_t)(kh * 128) * 1568 + col0;
        #pragma unroll 2
        for (int kl = 0; kl < 128; ++kl) {
            const float4 w4 = *(const float4*)(wp0 + (size_t)kl * 1568);
            float av[4];
            *(float4*)&av[0] = *(const float4*)&h1s[kl][4 * sq];
            const float wv[4] = {w4.x, w4.y, w4.z, w4.w};
            #pragma unroll
            for (int jc = 0; jc < 4; ++jc)
                #pragma unroll
                for (int ds = 0; ds < 4; ++ds)
                    acc[jc][ds] += wv[jc] * av[ds];
        }
        u16* h2h = h2g + (size_t)kh * H2_HALF;
        #pragma unroll
        for (int jc = 0; jc < 4; ++jc) {
            const int j = col0 + jc;
            const float bv = (kh == 0) ? b2g[j] : 0.f;
            const int ci = j / 49, rm = j % 49;
            const int iy = rm / 7, ix = rm % 7;
            const int off = ci * 56 + iy * 8 + ix;
            #pragma unroll
            for (int ds = 0; ds < 4; ++ds) {
                const int bb = sb[4 * sq + ds];
                if (bb >= 0)
                    h2h[(size_t)bb * H2_ELEMS + off] = f2bf(acc[jc][ds] + bv);
            }
        }
    }
}

// ---------------------------------------------------------------------------
// conv2 half-pass: output x in [14*H, 14*H+14) for one (co,y) row.
// ---------------------------------------------------------------------------
template <int H>
__device__ __forceinline__ void conv2_half(
    const float (*c1s)[14][20], u16 (*c2s)[28][30],
    const float* cw2g, const float bv, const int co, const int y)
{
    float acc[14];
    #pragma unroll
    for (int xx = 0; xx < 14; ++xx) acc[xx] = bv;
    const int a0 = (y + 1) & 1;
    for (int aa = 0; aa < 2; ++aa) {
        const int a = a0 + 2 * aa;
        const int iy = (y + 1 - a) >> 1;
        if ((unsigned)iy < 14u) {
            #pragma unroll 2
            for (int ci = 0; ci < 16; ++ci) {
                float rr[12];
                if (H == 0) {
                    *(float4*)&rr[0] = *(const float4*)&c1s[ci][iy][0];
                    *(float4*)&rr[4] = *(const float4*)&c1s[ci][iy][4];
                } else {
                    *(float4*)&rr[0] = *(const float4*)&c1s[ci][iy][4];
                    *(float4*)&rr[4] = *(const float4*)&c1s[ci][iy][8];
                    *(float4*)&rr[8] = *(const float4*)&c1s[ci][iy][12];
                }
                const float4 w4 = *(const float4*)(cw2g + ci * 128 + co * 16 + a * 4);
                const float wv[4] = {w4.x, w4.y, w4.z, w4.w};
                #pragma unroll
                for (int xx = 0; xx < 14; ++xx) {
                    const int x = 14 * H + xx;
                    const int c0v = (x + 1) & 1;
                    const int ix0 = (x + 1 - c0v) >> 1;
                    const int li = ix0 - 4 * H;
                    if (ix0 < 14) acc[xx] += rr[li] * wv[c0v];
                    if (ix0 >= 1) acc[xx] += rr[li - 1] * wv[c0v + 2];
                }
            }
        }
    }
    u32* dst = (u32*)&c2s[co][y][0];
    #pragma unroll
    for (int xx = 0; xx < 7; ++xx) {
        const u32 lo = f2bf(lrelu(acc[2 * xx]));
        const u32 hi = f2bf(lrelu(acc[2 * xx + 1]));
        dst[7 * H + xx] = lo | (hi << 16);
    }
}

// ---------------------------------------------------------------------------
// Kernel 4: all three transposed convs for ONE sample per block.
// Staging sums the two FC2 k-half partials and applies lrelu.
// LDS aliasing: c2s overlaps h2s (dead after conv1). ~31.4 KB total.
// ---------------------------------------------------------------------------
__global__ __launch_bounds__(256, 4) void conv_kernel(
    const int* __restrict__ g_idx,
    const float* __restrict__ cw1, const float* __restrict__ cb1,
    const float* __restrict__ cw2, const float* __restrict__ cb2,
    const float* __restrict__ cw3, const float* __restrict__ cb3,
    const u16* __restrict__ h2g, float* __restrict__ out)
{
    __shared__ __align__(16) char smem[13440 + 17920];  // 31.4 KB
    float (*h2s)[7][8]   = (float (*)[7][8])smem;       // [32][7][8], 7 KB
    u16  (*c2s)[28][30]  = (u16 (*)[28][30])smem;       // [8][28][30], 13.4 KB
    float (*c1s)[14][20] = (float (*)[14][20])(smem + 13440); // [16][14][20]
    __shared__ float w3s[72];

    const int tid = threadIdx.x;
    const int b = blockIdx.x;
    const int g = g_idx[b];
    const float* cw1g = cw1 + g * 8192;
    const float* cb1g = cb1 + g * 16;
    const float* cw2g = cw2 + g * 2048;
    const float* cb2g = cb2 + g * 8;
    const float* cw3g = cw3 + g * 72;
    const float  cb3v = cb3[g];

    // stage h2: sum bf16 k-half partials, lrelu, fp32 LDS. 224 thr x 8 elems
    if (tid < 224) {
        const uint4 qa = ((const uint4*)(h2g + (size_t)b * H2_ELEMS))[tid];
        const uint4 qb = ((const uint4*)(h2g + (size_t)H2_HALF + (size_t)b * H2_ELEMS))[tid];
        float* hp = (float*)h2s + 8 * tid;
        hp[0] = lrelu(bflo(qa.x) + bflo(qb.x));
        hp[1] = lrelu(bfhi(qa.x) + bfhi(qb.x));
        hp[2] = lrelu(bflo(qa.y) + bflo(qb.y));
        hp[3] = lrelu(bfhi(qa.y) + bfhi(qb.y));
        hp[4] = lrelu(bflo(qa.z) + bflo(qb.z));
        hp[5] = lrelu(bfhi(qa.z) + bfhi(qb.z));
        hp[6] = lrelu(bflo(qa.w) + bflo(qb.w));
        hp[7] = lrelu(bfhi(qa.w) + bfhi(qb.w));
    }
    if (tid < 72) w3s[tid] = cw3g[tid];
    __syncthreads();

    // conv1: [32,7,7] -> [16,14,14], k=4, s=2
    if (tid < 224) {
        const int co = tid / 14, y = tid % 14;
        float acc[14];
        const float bv = cb1g[co];
        #pragma unroll
        for (int x = 0; x < 14; ++x) acc[x] = bv;
        const int a0 = (y + 1) & 1;
        for (int aa = 0; aa < 2; ++aa) {
            const int a = a0 + 2 * aa;
            const int iy = (y + 1 - a) >> 1;
            if ((unsigned)iy < 7u) {
                #pragma unroll 2
                for (int ci = 0; ci < 32; ++ci) {
                    float rr[8];
                    *(float4*)&rr[0] = *(const float4*)&h2s[ci][iy][0];
                    *(float4*)&rr[4] = *(const float4*)&h2s[ci][iy][4];
                    const float4 w4 = *(const float4*)(cw1g + ci * 256 + co * 16 + a * 4);
                    const float wv[4] = {w4.x, w4.y, w4.z, w4.w};
                    #pragma unroll
                    for (int x = 0; x < 14; ++x) {
                        const int c0v = (x + 1) & 1;
                        const int ix0 = (x + 1 - c0v) >> 1;
                        if (ix0 < 7)  acc[x] += rr[ix0] * wv[c0v];
                        if (ix0 >= 1) acc[x] += rr[ix0 - 1] * wv[c0v + 2];
                    }
                }
            }
        }
        #pragma unroll
        for (int x = 0; x < 14; ++x) acc[x] = lrelu(acc[x]);
        *(float4*)&c1s[co][y][0]  = *(float4*)&acc[0];
        *(float4*)&c1s[co][y][4]  = *(float4*)&acc[4];
        *(float4*)&c1s[co][y][8]  = *(float4*)&acc[8];
        *(float2*)&c1s[co][y][12] = *(float2*)&acc[12];
    }
    __syncthreads();   // h2s dead beyond this point; c2s may now be written

    // conv2: [16,14,14] -> [8,28,28], k=4, s=2
    if (tid < 224) {
        const int co = tid / 28, y = tid % 28;
        const float bv = cb2g[co];
        conv2_half<0>(c1s, c2s, cw2g, bv, co, y);
        conv2_half<1>(c1s, c2s, cw2g, bv, co, y);
    }
    __syncthreads();

    // conv3: [8,28,28] -> [1,28,28], k=3, s=1, tanh
    if (tid < 196) {
        const int y = tid / 7, q = tid % 7;
        const int xb = q * 4;
        float acc[4] = {cb3v, cb3v, cb3v, cb3v};
        for (int ci = 0; ci < 8; ++ci) {
            float wv[9];
            #pragma unroll
            for (int j = 0; j < 9; ++j) wv[j] = w3s[ci * 9 + j];
            #pragma unroll
            for (int a = 0; a < 3; ++a) {
                const int iy = y + 1 - a;
                if ((unsigned)iy < 28u) {
                    float rr[6];
                    #pragma unroll
                    for (int j = 0; j < 6; ++j) {
                        const int ix = xb - 1 + j;
                        rr[j] = ((unsigned)ix < 28u) ? bf1(c2s[ci][iy][ix]) : 0.f;
                    }
                    #pragma unroll
                    for (int xx = 0; xx < 4; ++xx)
                        #pragma unroll
                        for (int c = 0; c < 3; ++c)
                            acc[xx] += rr[xx + 2 - c] * wv[a * 3 + c];
                }
            }
        }
        float* op = out + (size_t)b * 784 + y * 28 + xb;
        #pragma unroll
        for (int xx = 0; xx < 4; ++xx) op[xx] = fast_tanh(acc[xx]);
    }
}

extern "C" void kernel_launch(void* const* d_in, const int* in_sizes, int n_in,
                              void* d_out, int out_size, void* d_ws, size_t ws_size,
                              hipStream_t stream) {
    const float* z   = (const float*)d_in[0];
    const int*   gi  = (const int*)d_in[1];
    const float* W1  = (const float*)d_in[2];
    const float* b1  = (const float*)d_in[3];
    const float* W2  = (const float*)d_in[4];
    const float* b2  = (const float*)d_in[5];
    const float* cw1 = (const float*)d_in[6];
    const float* cb1 = (const float*)d_in[7];
    const float* cw2 = (const float*)d_in[8];
    const float* cb2 = (const float*)d_in[9];
    const float* cw3 = (const float*)d_in[10];
    const float* cb3 = (const float*)d_in[11];
    int*   wsi = (int*)d_ws;
    float* h1g = (float*)((char*)d_ws + WS_H1_OFF);
    u16*   h2g = (u16*)((char*)d_ws + WS_H2_OFF);

    bin_kernel<<<1, 256, 0, stream>>>(gi, wsi);
    fc1_kernel<<<MAXG, 256, 0, stream>>>(z, gi, W1, b1, wsi, h1g);
    fc2_kernel<<<MAXG * NCT * KS, 256, 0, stream>>>(gi, W2, b2, wsi, h1g, h2g);
    conv_kernel<<<BATCH, 256, 0, stream>>>(gi, cw1, cb1, cw2, cb2, cw3, cb3,
                                           h2g, (float*)d_out);
}

// Round 9
// 198.888 us; speedup vs baseline: 1.1639x; 1.1639x over previous
//
#include <hip/hip_runtime.h>
#include <cstdint>
#include <cstddef>

#define BATCH 2048
#define NZ 128
#define NGEN 8
#define GRPS 32                 // samples per group (same generator)
#define MAXG 72                 // max padded groups
#define NCT 13                  // fc2 col tiles of 128 (12 full + tail 32)
#define H2_ELEMS 1792           // 32*7*8 (x padded 7->8) per sample, bf16
#define WS_H1_OFF 16384
#define WS_H2_OFF (16384 + MAXG * 8192 * 4)

typedef unsigned int u32;
typedef unsigned short u16;
typedef _Float16 f16x8 __attribute__((ext_vector_type(8)));
typedef _Float16 f16x4 __attribute__((ext_vector_type(4)));
typedef float f32x4 __attribute__((ext_vector_type(4)));

__device__ __forceinline__ float lrelu(float x) { return fmaxf(x, 0.2f * x); }
__device__ __forceinline__ float bflo(u32 u) { union { u32 i; float f; } v; v.i = u << 16; return v.f; }
__device__ __forceinline__ float bfhi(u32 u) { union { u32 i; float f; } v; v.i = u & 0xffff0000u; return v.f; }
__device__ __forceinline__ float bf1(u16 u) { union { u32 i; float f; } v; v.i = ((u32)u) << 16; return v.f; }
__device__ __forceinline__ u16 f2bf(float f) {
    union { float f; u32 i; } v; v.f = f;
    u32 r = v.i + 0x7fffu + ((v.i >> 16) & 1u);   // round-to-nearest-even
    return (u16)(r >> 16);
}
__device__ __forceinline__ float fast_tanh(float x) {
    x = fminf(fmaxf(x, -9.f), 9.f);
    const float e = __expf(2.f * x);
    return (e - 1.f) / (e + 1.f);
}

// ---------------------------------------------------------------------------
// Kernel 1: bin samples by generator. wsi[0] = padded total;
// wsi[16..16+tot) = ids grouped by generator, groups padded to 32 with -1.
// ---------------------------------------------------------------------------
__global__ void bin_kernel(const int* __restrict__ g_idx, int* __restrict__ wsi) {
    __shared__ int cnt[NGEN];
    __shared__ int pbase[NGEN + 1];
    __shared__ u16 rank[BATCH];
    const int tid = threadIdx.x;
    if (tid < NGEN) cnt[tid] = 0;
    __syncthreads();
    for (int b = tid; b < BATCH; b += 256) {
        int g = g_idx[b];
        rank[b] = (u16)atomicAdd(&cnt[g], 1);
    }
    __syncthreads();
    if (tid == 0) {
        int acc = 0;
        for (int g = 0; g < NGEN; ++g) {
            pbase[g] = acc;
            acc += ((cnt[g] + GRPS - 1) / GRPS) * GRPS;
        }
        pbase[NGEN] = acc;
        wsi[0] = acc;
    }
    __syncthreads();
    const int total = pbase[NGEN];
    for (int i = tid; i < total; i += 256) wsi[16 + i] = -1;
    __syncthreads();
    for (int b = tid; b < BATCH; b += 256) {
        int g = g_idx[b];
        wsi[16 + pbase[g] + (int)rank[b]] = b;
    }
}

// ---------------------------------------------------------------------------
// Kernel 2: FC1, sample-split x4. Block = (group, 8-sample slice).
// Thread = one h1 column; 2 broadcast b128 z-reads per k (was 8).
// h1g layout [grp][sample 32][col 256] fp32 (sample-major for fc2 A-staging).
// Padded slots get z=0 -> h1 = lrelu(b1): deterministic, fc2-safe.
// ---------------------------------------------------------------------------
__global__ __launch_bounds__(256) void fc1_kernel(
    const float* __restrict__ z, const int* __restrict__ g_idx,
    const float* __restrict__ W1, const float* __restrict__ b1,
    const int* __restrict__ wsi, float* __restrict__ h1g)
{
    __shared__ float zst[NZ][12];   // 6 KB, [k][s] for 8 samples
    __shared__ int sb[8];
    __shared__ int sG;

    const int tid = threadIdx.x;
    const int grp = blockIdx.x >> 2;
    const int s0 = (blockIdx.x & 3) * 8;
    if (grp * GRPS >= wsi[0]) return;

    if (tid == 0) sG = g_idx[wsi[16 + grp * GRPS]];
    if (tid < 8) sb[tid] = wsi[16 + grp * GRPS + s0 + tid];
    __syncthreads();
    const float* W1g = W1 + sG * (NZ * 256);
    const float* b1g = b1 + sG * 256;

    {   // stage z: 8 samples x 128 = 256 float4, one per thread
        const int s = tid >> 5, f = tid & 31;
        float4 v = make_float4(0.f, 0.f, 0.f, 0.f);
        if (sb[s] >= 0) v = *(const float4*)(z + (size_t)sb[s] * NZ + 4 * f);
        zst[4 * f + 0][s] = v.x; zst[4 * f + 1][s] = v.y;
        zst[4 * f + 2][s] = v.z; zst[4 * f + 3][s] = v.w;
    }
    __syncthreads();

    const int c = tid;
    float acc[8];
    #pragma unroll
    for (int s = 0; s < 8; ++s) acc[s] = 0.f;
    const float* wp = W1g + c;
    #pragma unroll 4
    for (int k = 0; k < NZ; ++k) {
        const float w = wp[k * 256];
        float av[8];
        *(float4*)&av[0] = *(const float4*)&zst[k][0];
        *(float4*)&av[4] = *(const float4*)&zst[k][4];
        #pragma unroll
        for (int s = 0; s < 8; ++s) acc[s] += av[s] * w;
    }
    const float bv = b1g[c];
    float* hp = h1g + (size_t)grp * 8192 + (size_t)s0 * 256 + c;
    #pragma unroll
    for (int s = 0; s < 8; ++s) hp[s * 256] = lrelu(acc[s] + bv);
}

// ---------------------------------------------------------------------------
// Kernel 3: FC2 via fp16 MFMA 16x16x32. Block = (group, 128-col tile); 936
// blocks. A = h1 split hi+lo fp16 (staged frag-ordered in LDS: lane-contiguous
// b128 reads); B = W2 single fp16, loaded per-wave from global in B-frag
// order (each element read once per block). D = Ah*B + Al*B, fp32 acc.
// C/D layout: col(n)=lane&15, row(m)=(lane>>4)*4+reg [m89].
// Epilogue: +bias, lrelu, bf16 -> h2g [sample][ci*56+iy*8+ix]. No k-split.
// ---------------------------------------------------------------------------
__global__ __launch_bounds__(256) void fc2_kernel(
    const int* __restrict__ g_idx,
    const float* __restrict__ W2, const float* __restrict__ b2,
    const int* __restrict__ wsi, const float* __restrict__ h1g,
    u16* __restrict__ h2g)
{
    __shared__ _Float16 afrag[2 * 2 * 8 * 64 * 8];   // [mt][h][kq][lane][8], 32 KB
    __shared__ int sb[GRPS];
    __shared__ int sG;

    const int tid = threadIdx.x;
    const int grp = blockIdx.x / NCT;
    const int tile = blockIdx.x % NCT;
    if (grp * GRPS >= wsi[0]) return;

    if (tid == 0) sG = g_idx[wsi[16 + grp * GRPS]];
    if (tid < GRPS) sb[tid] = wsi[16 + grp * GRPS + tid];
    __syncthreads();
    const float* W2g = W2 + sG * (256 * 1568);
    const float* b2g = b2 + sG * 1568;

    // ---- stage A fragments (hi/lo split) ----
    {
        const float4* h1p4 = (const float4*)(h1g + (size_t)grp * 8192);
        #pragma unroll
        for (int i = 0; i < 8; ++i) {
            const int id4 = tid + 256 * i;
            const float4 v = h1p4[id4];
            const int s = id4 >> 6;            // 0..31
            const int kk = (id4 & 63) * 4;     // 0..252
            const int lane = ((kk >> 3) & 3) * 16 + (s & 15);
            const int mt = s >> 4, kq = kk >> 5, j = kk & 7;   // j in {0,4}
            const float vv[4] = {v.x, v.y, v.z, v.w};
            f16x4 hi, lo;
            #pragma unroll
            for (int e = 0; e < 4; ++e) {
                hi[e] = (_Float16)vv[e];
                lo[e] = (_Float16)(vv[e] - (float)hi[e]);
            }
            const int bh = (((mt * 2 + 0) * 8 + kq) * 64 + lane) * 8 + j;
            const int bl = (((mt * 2 + 1) * 8 + kq) * 64 + lane) * 8 + j;
            *(f16x4*)&afrag[bh] = hi;
            *(f16x4*)&afrag[bl] = lo;
        }
    }
    __syncthreads();

    const int wave = tid >> 6;
    const int lane = tid & 63;
    const int q = lane >> 4;      // k-quad
    const int nl = lane & 15;     // n within tile
    const int nb0 = tile * 128 + 2 * wave * 16;    // wave's first N-tile base
    const int nb1 = nb0 + 16;
    const bool v0 = nb0 < 1568, v1 = nb1 < 1568;
    if (!v0) return;              // tail waves idle (after staging+barrier)

    const int n0 = nb0 + nl, n1 = nb1 + nl;
    f32x4 acc00 = {0.f, 0.f, 0.f, 0.f}, acc10 = acc00, acc01 = acc00, acc11 = acc00;

    #pragma unroll
    for (int kq = 0; kq < 8; ++kq) {
        const int kbase = kq * 32 + q * 8;
        f16x8 b0, b1;
        const float* wp0 = W2g + (size_t)kbase * 1568 + n0;
        #pragma unroll
        for (int j = 0; j < 8; ++j) b0[j] = (_Float16)wp0[(size_t)j * 1568];
        if (v1) {
            const float* wp1 = W2g + (size_t)kbase * 1568 + n1;
            #pragma unroll
            for (int j = 0; j < 8; ++j) b1[j] = (_Float16)wp1[(size_t)j * 1568];
        }
        const f16x8 a0h = *(const f16x8*)&afrag[((0 * 8 + kq) * 64 + lane) * 8];
        const f16x8 a0l = *(const f16x8*)&afrag[((1 * 8 + kq) * 64 + lane) * 8];
        const f16x8 a1h = *(const f16x8*)&afrag[((2 * 8 + kq) * 64 + lane) * 8];
        const f16x8 a1l = *(const f16x8*)&afrag[((3 * 8 + kq) * 64 + lane) * 8];
        acc00 = __builtin_amdgcn_mfma_f32_16x16x32_f16(a0h, b0, acc00, 0, 0, 0);
        acc00 = __builtin_amdgcn_mfma_f32_16x16x32_f16(a0l, b0, acc00, 0, 0, 0);
        acc10 = __builtin_amdgcn_mfma_f32_16x16x32_f16(a1h, b0, acc10, 0, 0, 0);
        acc10 = __builtin_amdgcn_mfma_f32_16x16x32_f16(a1l, b0, acc10, 0, 0, 0);
        if (v1) {
            acc01 = __builtin_amdgcn_mfma_f32_16x16x32_f16(a0h, b1, acc01, 0, 0, 0);
            acc01 = __builtin_amdgcn_mfma_f32_16x16x32_f16(a0l, b1, acc01, 0, 0, 0);
            acc11 = __builtin_amdgcn_mfma_f32_16x16x32_f16(a1h, b1, acc11, 0, 0, 0);
            acc11 = __builtin_amdgcn_mfma_f32_16x16x32_f16(a1l, b1, acc11, 0, 0, 0);
        }
    }

    // ---- epilogue ----
    #pragma unroll
    for (int nt = 0; nt < 2; ++nt) {
        if (nt == 1 && !v1) break;
        const int n = nt ? n1 : n0;
        const float bias = b2g[n];
        const int ci = n / 49, rm = n % 49;
        const int off = ci * 56 + (rm / 7) * 8 + (rm % 7);
        #pragma unroll
        for (int mt = 0; mt < 2; ++mt) {
            const f32x4 a = (nt == 0) ? (mt == 0 ? acc00 : acc10)
                                      : (mt == 0 ? acc01 : acc11);
            #pragma unroll
            for (int reg = 0; reg < 4; ++reg) {
                const int s = mt * 16 + q * 4 + reg;
                const int bb = sb[s];
                if (bb >= 0)
                    h2g[(size_t)bb * H2_ELEMS + off] = f2bf(lrelu(a[reg] + bias));
            }
        }
    }
}

// ---------------------------------------------------------------------------
// conv2 half-pass: output x in [14*H, 14*H+14) for one (co,y) row.
// ---------------------------------------------------------------------------
template <int H>
__device__ __forceinline__ void conv2_half(
    const float (*c1s)[14][20], u16 (*c2s)[28][30],
    const float* cw2g, const float bv, const int co, const int y)
{
    float acc[14];
    #pragma unroll
    for (int xx = 0; xx < 14; ++xx) acc[xx] = bv;
    const int a0 = (y + 1) & 1;
    for (int aa = 0; aa < 2; ++aa) {
        const int a = a0 + 2 * aa;
        const int iy = (y + 1 - a) >> 1;
        if ((unsigned)iy < 14u) {
            #pragma unroll 2
            for (int ci = 0; ci < 16; ++ci) {
                float rr[12];
                if (H == 0) {
                    *(float4*)&rr[0] = *(const float4*)&c1s[ci][iy][0];
                    *(float4*)&rr[4] = *(const float4*)&c1s[ci][iy][4];
                } else {
                    *(float4*)&rr[0] = *(const float4*)&c1s[ci][iy][4];
                    *(float4*)&rr[4] = *(const float4*)&c1s[ci][iy][8];
                    *(float4*)&rr[8] = *(const float4*)&c1s[ci][iy][12];
                }
                const float4 w4 = *(const float4*)(cw2g + ci * 128 + co * 16 + a * 4);
                const float wv[4] = {w4.x, w4.y, w4.z, w4.w};
                #pragma unroll
                for (int xx = 0; xx < 14; ++xx) {
                    const int x = 14 * H + xx;
                    const int c0v = (x + 1) & 1;
                    const int ix0 = (x + 1 - c0v) >> 1;
                    const int li = ix0 - 4 * H;
                    if (ix0 < 14) acc[xx] += rr[li] * wv[c0v];
                    if (ix0 >= 1) acc[xx] += rr[li - 1] * wv[c0v + 2];
                }
            }
        }
    }
    u32* dst = (u32*)&c2s[co][y][0];
    #pragma unroll
    for (int xx = 0; xx < 7; ++xx) {
        const u32 lo = f2bf(lrelu(acc[2 * xx]));
        const u32 hi = f2bf(lrelu(acc[2 * xx + 1]));
        dst[7 * H + xx] = lo | (hi << 16);
    }
}

// ---------------------------------------------------------------------------
// Kernel 4: all three transposed convs, ONE sample per block.
// h2 already post-lrelu bf16. LDS aliasing: c2s over dead h2s. ~31.4 KB.
// launch_bounds(256,5): 5 blocks/CU (5 x 31.7 KB = 158.7 <= 160 KB LDS).
// ---------------------------------------------------------------------------
__global__ __launch_bounds__(256, 5) void conv_kernel(
    const int* __restrict__ g_idx,
    const float* __restrict__ cw1, const float* __restrict__ cb1,
    const float* __restrict__ cw2, const float* __restrict__ cb2,
    const float* __restrict__ cw3, const float* __restrict__ cb3,
    const u16* __restrict__ h2g, float* __restrict__ out)
{
    __shared__ __align__(16) char smem[13440 + 17920];
    float (*h2s)[7][8]   = (float (*)[7][8])smem;            // [32][7][8]
    u16  (*c2s)[28][30]  = (u16 (*)[28][30])smem;            // [8][28][30]
    float (*c1s)[14][20] = (float (*)[14][20])(smem + 13440);
    __shared__ float w3s[72];

    const int tid = threadIdx.x;
    const int b = blockIdx.x;
    const int g = g_idx[b];
    const float* cw1g = cw1 + g * 8192;
    const float* cb1g = cb1 + g * 16;
    const float* cw2g = cw2 + g * 2048;
    const float* cb2g = cb2 + g * 8;
    const float* cw3g = cw3 + g * 72;
    const float  cb3v = cb3[g];

    if (tid < 224) {
        const uint4 qv = ((const uint4*)(h2g + (size_t)b * H2_ELEMS))[tid];
        float* hp = (float*)h2s + 8 * tid;
        ((float4*)hp)[0] = make_float4(bflo(qv.x), bfhi(qv.x), bflo(qv.y), bfhi(qv.y));
        ((float4*)hp)[1] = make_float4(bflo(qv.z), bfhi(qv.z), bflo(qv.w), bfhi(qv.w));
    }
    if (tid < 72) w3s[tid] = cw3g[tid];
    __syncthreads();

    // conv1: [32,7,7] -> [16,14,14], k=4, s=2
    if (tid < 224) {
        const int co = tid / 14, y = tid % 14;
        float acc[14];
        const float bv = cb1g[co];
        #pragma unroll
        for (int x = 0; x < 14; ++x) acc[x] = bv;
        const int a0 = (y + 1) & 1;
        for (int aa = 0; aa < 2; ++aa) {
            const int a = a0 + 2 * aa;
            const int iy = (y + 1 - a) >> 1;
            if ((unsigned)iy < 7u) {
                #pragma unroll 2
                for (int ci = 0; ci < 32; ++ci) {
                    float rr[8];
                    *(float4*)&rr[0] = *(const float4*)&h2s[ci][iy][0];
                    *(float4*)&rr[4] = *(const float4*)&h2s[ci][iy][4];
                    const float4 w4 = *(const float4*)(cw1g + ci * 256 + co * 16 + a * 4);
                    const float wv[4] = {w4.x, w4.y, w4.z, w4.w};
                    #pragma unroll
                    for (int x = 0; x < 14; ++x) {
                        const int c0v = (x + 1) & 1;
                        const int ix0 = (x + 1 - c0v) >> 1;
                        if (ix0 < 7)  acc[x] += rr[ix0] * wv[c0v];
                        if (ix0 >= 1) acc[x] += rr[ix0 - 1] * wv[c0v + 2];
                    }
                }
            }
        }
        #pragma unroll
        for (int x = 0; x < 14; ++x) acc[x] = lrelu(acc[x]);
        *(float4*)&c1s[co][y][0]  = *(float4*)&acc[0];
        *(float4*)&c1s[co][y][4]  = *(float4*)&acc[4];
        *(float4*)&c1s[co][y][8]  = *(float4*)&acc[8];
        *(float2*)&c1s[co][y][12] = *(float2*)&acc[12];
    }
    __syncthreads();   // h2s dead; c2s may be written

    if (tid < 224) {
        const int co = tid / 28, y = tid % 28;
        const float bv = cb2g[co];
        conv2_half<0>(c1s, c2s, cw2g, bv, co, y);
        conv2_half<1>(c1s, c2s, cw2g, bv, co, y);
    }
    __syncthreads();

    if (tid < 196) {
        const int y = tid / 7, qq = tid % 7;
        const int xb = qq * 4;
        float acc[4] = {cb3v, cb3v, cb3v, cb3v};
        for (int ci = 0; ci < 8; ++ci) {
            float wv[9];
            #pragma unroll
            for (int j = 0; j < 9; ++j) wv[j] = w3s[ci * 9 + j];
            #pragma unroll
            for (int a = 0; a < 3; ++a) {
                const int iy = y + 1 - a;
                if ((unsigned)iy < 28u) {
                    float rr[6];
                    #pragma unroll
                    for (int j = 0; j < 6; ++j) {
                        const int ix = xb - 1 + j;
                        rr[j] = ((unsigned)ix < 28u) ? bf1(c2s[ci][iy][ix]) : 0.f;
                    }
                    #pragma unroll
                    for (int xx = 0; xx < 4; ++xx)
                        #pragma unroll
                        for (int c = 0; c < 3; ++c)
                            acc[xx] += rr[xx + 2 - c] * wv[a * 3 + c];
                }
            }
        }
        float* op = out + (size_t)b * 784 + y * 28 + xb;
        #pragma unroll
        for (int xx = 0; xx < 4; ++xx) op[xx] = fast_tanh(acc[xx]);
    }
}

extern "C" void kernel_launch(void* const* d_in, const int* in_sizes, int n_in,
                              void* d_out, int out_size, void* d_ws, size_t ws_size,
                              hipStream_t stream) {
    const float* z   = (const float*)d_in[0];
    const int*   gi  = (const int*)d_in[1];
    const float* W1  = (const float*)d_in[2];
    const float* b1  = (const float*)d_in[3];
    const float* W2  = (const float*)d_in[4];
    const float* b2  = (const float*)d_in[5];
    const float* cw1 = (const float*)d_in[6];
    const float* cb1 = (const float*)d_in[7];
    const float* cw2 = (const float*)d_in[8];
    const float* cb2 = (const float*)d_in[9];
    const float* cw3 = (const float*)d_in[10];
    const float* cb3 = (const float*)d_in[11];
    int*   wsi = (int*)d_ws;
    float* h1g = (float*)((char*)d_ws + WS_H1_OFF);
    u16*   h2g = (u16*)((char*)d_ws + WS_H2_OFF);

    bin_kernel<<<1, 256, 0, stream>>>(gi, wsi);
    fc1_kernel<<<MAXG * 4, 256, 0, stream>>>(z, gi, W1, b1, wsi, h1g);
    fc2_kernel<<<MAXG * NCT, 256, 0, stream>>>(gi, W2, b2, wsi, h1g, h2g);
    conv_kernel<<<BATCH, 256, 0, stream>>>(gi, cw1, cb1, cw2, cb2, cw3, cb3,
                                           h2g, (float*)d_out);
}